// Round 1
// baseline (485.276 us; speedup 1.0000x reference)
//
#include <hip/hip_runtime.h>

#define Bb 8
#define Ll 2048
#define Hh 1024

typedef __bf16 bf16;
typedef __attribute__((ext_vector_type(8))) __bf16 bf16x8;
typedef __attribute__((ext_vector_type(4))) __bf16 bf16x4;
typedef __attribute__((ext_vector_type(4))) float f32x4;

__device__ __forceinline__ void gload16(const bf16* src, bf16* dst) {
  __builtin_amdgcn_global_load_lds(
      (const __attribute__((address_space(1))) void*)src,
      (__attribute__((address_space(3))) void*)dst, 16, 0, 0);
}

// ---------------------------------------------------------------------------
// Split X (f32) -> Xhi, Xlo (bf16, [b][l][h]) and XT (bf16 hi, [b][h][l])
// ---------------------------------------------------------------------------
__global__ __launch_bounds__(256) void split_x_k(
    const float* __restrict__ X, bf16* __restrict__ Xhi,
    bf16* __restrict__ Xlo, bf16* __restrict__ XT) {
  __shared__ float tile[64][65];
  const int h0 = blockIdx.x << 6, l0 = blockIdx.y << 6, b = blockIdx.z;
  const int t = threadIdx.x;
  const int c = t & 63, r0 = t >> 6;
  const float* Xb = X + ((long)b * Ll + l0) * Hh + h0;
  bf16* XhiB = Xhi + ((long)b * Ll + l0) * Hh + h0;
  bf16* XloB = Xlo + ((long)b * Ll + l0) * Hh + h0;
#pragma unroll
  for (int i = 0; i < 16; ++i) {
    int row = (i << 2) + r0;
    float x = Xb[(long)row * Hh + c];
    bf16 hi = (bf16)x;
    XhiB[(long)row * Hh + c] = hi;
    XloB[(long)row * Hh + c] = (bf16)(x - (float)hi);
    tile[row][c] = x;
  }
  __syncthreads();
  bf16* XTB = XT + ((long)b * Hh + h0) * Ll + l0;
#pragma unroll
  for (int i = 0; i < 16; ++i) {
    int row = (i << 2) + r0;  // h index
    XTB[(long)row * Ll + c] = (bf16)tile[c][row];
  }
}

// ---------------------------------------------------------------------------
// Split W (f32 [o][h]) -> Whi, Wlo
// ---------------------------------------------------------------------------
__global__ __launch_bounds__(256) void split_w_k(
    const float* __restrict__ W, bf16* __restrict__ Whi,
    bf16* __restrict__ Wlo) {
  int i = blockIdx.x * 256 + threadIdx.x;
  float4 v = ((const float4*)W)[i];
  bf16 h0 = (bf16)v.x, h1 = (bf16)v.y, h2 = (bf16)v.z, h3 = (bf16)v.w;
  bf16x4 hv = {h0, h1, h2, h3};
  bf16x4 lv = {(bf16)(v.x - (float)h0), (bf16)(v.y - (float)h1),
               (bf16)(v.z - (float)h2), (bf16)(v.w - (float)h3)};
  *(bf16x4*)&Whi[i * 4] = hv;
  *(bf16x4*)&Wlo[i * 4] = lv;
}

// ---------------------------------------------------------------------------
// NT GEMM, 128x128 tile, BK=64, 4 waves, 16x16x32 bf16 MFMA.
// SPLIT: 3-pass bf16x2 (hi*hi + hi*lo + lo*hi) for ~f32 accuracy.
// EPI 0: bias add + split-store bf16 pair (Qhi,Qlo)
// EPI 1: relu + f32 store
// EPI 2: f32 store
// LDS layout: linear dest for global_load_lds; source pre-swizzled with
// col16 ^= (row&7); reads apply the same involution (G4 / rule 21).
// ---------------------------------------------------------------------------
template <int EPI, bool SPLIT>
__global__ __launch_bounds__(256, 2) void gemm_nt(
    const bf16* __restrict__ Ahi, const bf16* __restrict__ Alo,
    const bf16* __restrict__ Bhi, const bf16* __restrict__ Blo, int N, int K,
    long sA_, long sB_, long sC_, float* __restrict__ outF,
    bf16* __restrict__ outHi, bf16* __restrict__ outLo,
    const float* __restrict__ bias) {
  constexpr int NS = SPLIT ? 2 : 1;
  __shared__ bf16 sA[NS][128 * 64];
  __shared__ bf16 sB[NS][128 * 64];
  const int b = blockIdx.z;
  const int m0 = blockIdx.y * 128;
  const int n0 = blockIdx.x * 128;
  Ahi += (long)b * sA_ + (long)m0 * K;
  Bhi += (long)b * sB_ + (long)n0 * K;
  const bf16 *AloP = nullptr, *BloP = nullptr;
  if constexpr (SPLIT) {
    AloP = Alo + (long)b * sA_ + (long)m0 * K;
    BloP = Blo + (long)b * sB_ + (long)n0 * K;
  }

  const int t = threadIdx.x;
  const int lane = t & 63;
  const int w = t >> 6;
  const int wr = (w >> 1) * 64, wc = (w & 1) * 64;
  const int g = lane >> 4;
  const int fr = lane & 15;

  f32x4 acc[4][4];
#pragma unroll
  for (int m = 0; m < 4; ++m)
#pragma unroll
    for (int n = 0; n < 4; ++n) acc[m][n] = {0.f, 0.f, 0.f, 0.f};

  // staging address precompute: chunk c = p*256+t covers LDS bytes [c*16,+16)
  int srow[4], soff[4];
#pragma unroll
  for (int p = 0; p < 4; ++p) {
    int c = p * 256 + t;
    int row = c >> 3;
    soff[p] = ((c & 7) ^ (row & 7)) * 8;  // pre-swizzled source column (elems)
    srow[p] = row;
  }

  for (int kt = 0; kt < K; kt += 64) {
#pragma unroll
    for (int p = 0; p < 4; ++p) {
      const long go = (long)srow[p] * K + kt + soff[p];
      const int lo_ = (p * 256 + t) * 8;
      gload16(Ahi + go, &sA[0][lo_]);
      gload16(Bhi + go, &sB[0][lo_]);
      if constexpr (SPLIT) {
        gload16(AloP + go, &sA[1][lo_]);
        gload16(BloP + go, &sB[1][lo_]);
      }
    }
    __syncthreads();  // drains vmcnt before barrier (compiler-enforced)
#pragma unroll
    for (int ks = 0; ks < 2; ++ks) {
      bf16x8 ah[4], bh[4], al[4], bl[4];
#pragma unroll
      for (int m = 0; m < 4; ++m) {
        int row = wr + m * 16 + fr;
        int idx = row * 64 + ((((ks << 2) | g) ^ (row & 7)) << 3);
        ah[m] = *(const bf16x8*)&sA[0][idx];
        if constexpr (SPLIT) al[m] = *(const bf16x8*)&sA[1][idx];
      }
#pragma unroll
      for (int n = 0; n < 4; ++n) {
        int row = wc + n * 16 + fr;
        int idx = row * 64 + ((((ks << 2) | g) ^ (row & 7)) << 3);
        bh[n] = *(const bf16x8*)&sB[0][idx];
        if constexpr (SPLIT) bl[n] = *(const bf16x8*)&sB[1][idx];
      }
#pragma unroll
      for (int m = 0; m < 4; ++m)
#pragma unroll
        for (int n = 0; n < 4; ++n) {
          acc[m][n] =
              __builtin_amdgcn_mfma_f32_16x16x32_bf16(ah[m], bh[n], acc[m][n], 0, 0, 0);
          if constexpr (SPLIT) {
            acc[m][n] = __builtin_amdgcn_mfma_f32_16x16x32_bf16(ah[m], bl[n],
                                                                acc[m][n], 0, 0, 0);
            acc[m][n] = __builtin_amdgcn_mfma_f32_16x16x32_bf16(al[m], bh[n],
                                                                acc[m][n], 0, 0, 0);
          }
        }
    }
    __syncthreads();
  }

  // epilogue; C/D layout: col = lane&15, row = (lane>>4)*4 + reg  [m89]
  const int crow0 = m0 + wr + (lane >> 4) * 4;
  const int ccol0 = n0 + wc + fr;
#pragma unroll
  for (int m = 0; m < 4; ++m)
#pragma unroll
    for (int n = 0; n < 4; ++n)
#pragma unroll
      for (int j = 0; j < 4; ++j) {
        const int r = crow0 + m * 16 + j;
        const int cc = ccol0 + n * 16;
        float v = acc[m][n][j];
        const long off = (long)b * sC_ + (long)r * N + cc;
        if constexpr (EPI == 0) {
          v += bias[cc];
          bf16 hi = (bf16)v;
          outHi[off] = hi;
          outLo[off] = (bf16)(v - (float)hi);
        } else if constexpr (EPI == 1) {
          outF[off] = v > 0.f ? v : 0.f;
        } else {
          outF[off] = v;
        }
      }
}

// ---------------------------------------------------------------------------
// Row softmax (input already relu'd) + mask add, in place; also bf16 copy.
// One block per row of 2048.
// ---------------------------------------------------------------------------
__global__ __launch_bounds__(256) void softmax_mask_k(
    float* __restrict__ U, const float* __restrict__ mask,
    bf16* __restrict__ Abf) {
  __shared__ float red[8];
  const long row = blockIdx.x;
  float* u = U + row * 2048;
  const float* mk = mask + row * 2048;
  bf16* ab = Abf + row * 2048;
  const int t = threadIdx.x;
  float4 v0 = *(const float4*)(u + t * 4);
  float4 v1 = *(const float4*)(u + 1024 + t * 4);
  float m = fmaxf(fmaxf(fmaxf(v0.x, v0.y), fmaxf(v0.z, v0.w)),
                  fmaxf(fmaxf(v1.x, v1.y), fmaxf(v1.z, v1.w)));
#pragma unroll
  for (int s = 32; s; s >>= 1) m = fmaxf(m, __shfl_xor(m, s));
  if ((t & 63) == 0) red[t >> 6] = m;
  __syncthreads();
  m = fmaxf(fmaxf(red[0], red[1]), fmaxf(red[2], red[3]));
  float e0 = __expf(v0.x - m), e1 = __expf(v0.y - m), e2 = __expf(v0.z - m),
        e3 = __expf(v0.w - m);
  float e4 = __expf(v1.x - m), e5 = __expf(v1.y - m), e6 = __expf(v1.z - m),
        e7 = __expf(v1.w - m);
  float s = ((e0 + e1) + (e2 + e3)) + ((e4 + e5) + (e6 + e7));
#pragma unroll
  for (int sh = 32; sh; sh >>= 1) s += __shfl_xor(s, sh);
  if ((t & 63) == 0) red[4 + (t >> 6)] = s;
  __syncthreads();
  s = (red[4] + red[5]) + (red[6] + red[7]);
  const float inv = 1.0f / s;
  float4 k0 = *(const float4*)(mk + t * 4);
  float4 k1 = *(const float4*)(mk + 1024 + t * 4);
  float4 a0 = {e0 * inv + k0.x, e1 * inv + k0.y, e2 * inv + k0.z,
               e3 * inv + k0.w};
  float4 a1 = {e4 * inv + k1.x, e5 * inv + k1.y, e6 * inv + k1.z,
               e7 * inv + k1.w};
  *(float4*)(u + t * 4) = a0;
  *(float4*)(u + 1024 + t * 4) = a1;
  bf16x4 b0 = {(bf16)a0.x, (bf16)a0.y, (bf16)a0.z, (bf16)a0.w};
  bf16x4 b1 = {(bf16)a1.x, (bf16)a1.y, (bf16)a1.z, (bf16)a1.w};
  *(bf16x4*)(ab + t * 4) = b0;
  *(bf16x4*)(ab + 1024 + t * 4) = b1;
}

// ---------------------------------------------------------------------------
extern "C" void kernel_launch(void* const* d_in, const int* in_sizes, int n_in,
                              void* d_out, int out_size, void* d_ws,
                              size_t ws_size, hipStream_t stream) {
  const float* X = (const float*)d_in[0];
  const float* mask = (const float*)d_in[1];
  const float* W = (const float*)d_in[2];
  const float* bias = (const float*)d_in[3];
  float* out_h = (float*)d_out;
  float* out_a = out_h + (size_t)Bb * Ll * Hh;

  const size_t NX = (size_t)Bb * Ll * Hh;  // 16,777,216
  const size_t NA = (size_t)Bb * Ll * Ll;  // 33,554,432
  bf16* Xhi = (bf16*)d_ws;
  bf16* Xlo = Xhi + NX;
  bf16* XT = Xlo + NX;
  bf16* Qhi = XT + NX;
  bf16* Qlo = Qhi + NX;
  bf16* Abf = Qlo + NX;
  bf16* Whi = Abf + NA;
  bf16* Wlo = Whi + (size_t)Hh * Hh;
  // total ws: 239,075,328 bytes

  split_x_k<<<dim3(Hh / 64, Ll / 64, Bb), 256, 0, stream>>>(X, Xhi, Xlo, XT);
  split_w_k<<<dim3((Hh * Hh / 4) / 256), 256, 0, stream>>>(W, Whi, Wlo);
  // GEMM1: Q = X W^T + b  (M=16384, N=1024, K=1024), split 3-pass
  gemm_nt<0, true><<<dim3(Hh / 128, (Bb * Ll) / 128, 1), 256, 0, stream>>>(
      Xhi, Xlo, Whi, Wlo, Hh, Hh, 0, 0, 0, nullptr, Qhi, Qlo, bias);
  // GEMM2: U = relu(Q X^T) per batch (M=2048, N=2048, K=1024) -> out_a region
  gemm_nt<1, true><<<dim3(Ll / 128, Ll / 128, Bb), 256, 0, stream>>>(
      Qhi, Qlo, Xhi, Xlo, Ll, Hh, (long)Ll * Hh, (long)Ll * Hh, (long)Ll * Ll,
      out_a, nullptr, nullptr, nullptr);
  // softmax + mask, in place over out_a; bf16 copy to Abf
  softmax_mask_k<<<dim3(Bb * Ll), 256, 0, stream>>>(out_a, mask, Abf);
  // GEMM3: H = A X per batch (M=2048, N=1024, K=2048), plain bf16 NT vs X^T
  gemm_nt<2, false><<<dim3(Hh / 128, Ll / 128, Bb), 256, 0, stream>>>(
      Abf, nullptr, XT, nullptr, Hh, Ll, (long)Ll * Ll, (long)Hh * Ll,
      (long)Ll * Hh, out_h, nullptr, nullptr, nullptr);
}